// Round 15
// baseline (102.062 us; speedup 1.0000x reference)
//
#include <hip/hip_runtime.h>
#include <hip/hip_bf16.h>
#include <math.h>

#define N_IMG 8192
#define GROUPS 16
#define EMB 1600
#define IPB 8

typedef __attribute__((ext_vector_type(8))) short short8;
typedef __attribute__((ext_vector_type(16))) float f32x16;
typedef __attribute__((ext_vector_type(4))) unsigned int u32x4;
typedef __attribute__((ext_vector_type(8))) int i32x8;

// ws layout (bytes): gsum[25600 f32]@0 ; w2f8[20480 u8]@102400 ;
//                    w1f[512 bf16]@122880 ; v[1600 f32]@123904
#define WS_W2F8 102400
#define WS_W1F  122880
#define WS_V    123904

__device__ __forceinline__ unsigned short bfc(float f) {
    return __builtin_bit_cast(unsigned short, __float2bfloat16(f));
}
__device__ __forceinline__ unsigned pk2(float a, float b) {
    return (unsigned)bfc(a) | ((unsigned)bfc(b) << 16);
}
__device__ __forceinline__ unsigned char f2fp8(float f) {
    return (unsigned char)(__builtin_amdgcn_cvt_pk_fp8_f32(f, f, 0, false) & 0xFF);
}

// ---------------------------------------------------------------------------
// prep: zero gsum [0,25600) ; pack w2 -> fp8 frag order [25600,46080) ;
// pack w1 bf16 frags [46080,46592) ; v = fc1w @ fc2w with one WAVE per
// output d (coalesced row reads + butterfly reduce) [46592,148992).
// All range starts 64-aligned so waves never straddle roles.
// ---------------------------------------------------------------------------
__global__ __launch_bounds__(256) void prep(
        const float* __restrict__ w1, const float* __restrict__ w2,
        const float* __restrict__ fc1w, const float* __restrict__ fc2w,
        float* __restrict__ gsum, unsigned short* __restrict__ w1f,
        unsigned char* __restrict__ w2f8, float* __restrict__ v)
{
    int gid = blockIdx.x * 256 + threadIdx.x;
    if (gid < 25600) { gsum[gid] = 0.f; return; }
    if (gid < 46080) {
        int i = gid - 25600;
        int u = i & 31, n = (i >> 5) & 63, t = i >> 11;
        unsigned char q = 0;
        if (t < 9) q = f2fp8(w2[(t * 32 + u) * 64 + n]);
        w2f8[i] = q;
        return;
    }
    if (gid < 46592) {
        int i = gid - 46080;
        int j = i & 7, ll = i >> 3;
        int k = 8 * (ll >> 5) + j;
        int r = k >> 2, c4 = k & 3, co = ll & 31;
        w1f[i] = (r < 3 && c4 < 3) ? bfc(w1[(r * 3 + c4) * 32 + co])
                                   : (unsigned short)0;
        return;
    }
    {
        const int d = (gid - 46592) >> 6;
        if (d < 1600) {
            const int lane = gid & 63;
            const float4* a = (const float4*)(fc1w + d * 512 + lane * 8);
            const float4* b = (const float4*)(fc2w + lane * 8);
            const float4 a0 = a[0], a1 = a[1], b0 = b[0], b1 = b[1];
            float s = a0.x * b0.x + a0.y * b0.y + a0.z * b0.z + a0.w * b0.w
                    + a1.x * b1.x + a1.y * b1.y + a1.z * b1.z + a1.w * b1.w;
            #pragma unroll
            for (int off = 32; off; off >>= 1) s += __shfl_xor(s, off);
            if (lane == 0) v[d] = s;
        }
    }
}

// ---------------------------------------------------------------------------
// Fused: 4 waves/block, IPB=8 images, 1 barrier/image (buffer parity),
// conv1 = bf16 32x32x16 MFMA (unchanged from R11, absmax-0-proven).
// conv2 RESTRUCTURED M-only: wave wv owns M-tile wv x BOTH N-halves; the
// A-read redundancy between N-split waves is gone (80 -> 40 b128/img/block);
// B streams from w2f8 in global (20KB, L1-resident; VMEM pipe idle).
// Numerics bitwise-identical to R11 (same bytes, same MFMA order).
// __launch_bounds__(256,4) pins the <=128-VGPR occupancy class.
// ---------------------------------------------------------------------------
__global__ __launch_bounds__(256, 4) void fused(
        const float* __restrict__ x,
        const unsigned short* __restrict__ w1f, const float* __restrict__ b1,
        const unsigned char* __restrict__ w2f8, const float* __restrict__ b2,
        float* __restrict__ gsum)
{
    __shared__ __align__(16) unsigned short simgb[2 * 1568];  // [dbuf][copy0|copy1]
    __shared__ __align__(16) unsigned char sp2[2 * 6912];     // [dbuf][144 pos][48B]

    const int tid = threadIdx.x;
    const int wv = tid >> 6;
    const int l = tid & 63;
    const int l31 = l & 31, lh = l >> 5;

    // conv1 B-frag
    const short8 wb1 = *(const short8*)(w1f + l * 8);
    const float cb1 = b1[l31];

    // conv2: per-lane global byte offset into w2f8 (chunk c adds 4096c, half j adds 1024)
    const int bgo = 2048 * lh + 32 * l31;
    const float cb20 = b2[l31], cb21 = b2[32 + l31];

    // ---- lane-invariant integer BYTE offsets ----
    const int rb_inv = 2 * ((l & 1) * 784 + ((l >> 1) & 1) * 28 + 56 * lh);
    const int wb_inv = 384 * wv + 48 * lh + l31;        // conv1 fp8 write base
    const int ew = 8 * wv + (l31 >> 2);
    // conv2 A row base for this wave's M-tile (mt = wv)
    int posq;
    {
        int m2 = 32 * wv + l31; if (m2 > 99) m2 = 99;
        const int q2i = m2 >> 2, idx2 = m2 & 3;
        posq = ((2 * (q2i / 5) + (idx2 >> 1)) * 12 + 2 * (q2i % 5) + (idx2 & 1)) * 48;
    }
    // chunk tap row offsets: tap = 2c+lh, shift(t) = ((t/3)*12 + t%3)*48
    const int o0 = lh ? 48   : 0;
    const int o1 = lh ? 576  : 96;
    const int o2 = lh ? 672  : 624;
    const int o3 = lh ? 1200 : 1152;
    const int o4 = lh ? 0    : 1248;   // tap 9 (zero weights) reads base row

    float pacc0[4] = {0.f, 0.f, 0.f, 0.f};
    float pacc1[4] = {0.f, 0.f, 0.f, 0.f};

    const int imgbase = blockIdx.x * IPB;
    const float* xbase = x + (size_t)imgbase * 784;

    // prologue: pack image 0 into buffer 0 (copy0 + 1-px-shifted copy1)
    if (tid < 98) {
        const float4* xg = (const float4*)xbase;
        float4 A = xg[2 * tid], B = xg[2 * tid + 1];
        float sc = xbase[(8 * tid + 8 < 784) ? 8 * tid + 8 : 783];
        *(u32x4*)(&simgb[8 * tid]) =
            (u32x4){pk2(A.x, A.y), pk2(A.z, A.w), pk2(B.x, B.y), pk2(B.z, B.w)};
        *(u32x4*)(&simgb[784 + 8 * tid]) =
            (u32x4){pk2(A.y, A.z), pk2(A.w, B.x), pk2(B.y, B.z), pk2(B.w, sc)};
    }
    asm volatile("s_waitcnt lgkmcnt(0)" ::: "memory");
    __builtin_amdgcn_s_barrier();

    for (int ii = 0; ii < IPB; ++ii) {
        const int SOFF = (ii & 1) * 3136;   // simgb dbuf BYTE offset
        const int POFF = (ii & 1) * 6912;   // sp2 dbuf BYTE offset
        const char* rb = (const char*)simgb + (SOFF + rb_inv);
        unsigned char* wb = sp2 + (POFF + wb_inv);

        // issue next-image global loads early
        float4 A4, B4; float sc = 0.f;
        const bool pf = (ii + 1 < IPB) && (tid < 98);
        if (pf) {
            const float4* xn = (const float4*)(xbase + (ii + 1) * 784);
            A4 = xn[2 * tid]; B4 = xn[2 * tid + 1];
            sc = xbase[(ii + 1) * 784 + ((8 * tid + 8 < 784) ? 8 * tid + 8 : 783)];
        }

        // ---- conv1: tiles t = 4*t9 + wv (bf16 MFMA), fp8 pooled writes ----
        #pragma unroll
        for (int t9 = 0; t9 < 5; ++t9) {
            if (4 * t9 + wv < 18) {
                const int qd = 32 * t9 + ew;
                const int pr = qd / 12, pc = qd - 12 * pr;
                const unsigned* bp = (const unsigned*)(rb + (112 * pr + 4 * pc));
                const unsigned d0 = bp[0], d1 = bp[1], d2 = bp[14], d3 = bp[15];
                const short8 af = __builtin_bit_cast(short8, (u32x4){d0, d1, d2, d3});
                f32x16 cc;
                #pragma unroll
                for (int z = 0; z < 16; ++z) cc[z] = cb1;
                cc = __builtin_amdgcn_mfma_f32_32x32x16_bf16(af, wb1, cc, 0, 0, 0);
                #pragma unroll
                for (int rq = 0; rq < 4; ++rq) {
                    float p = fmaxf(fmaxf(fmaxf(fmaxf(cc[4 * rq], cc[4 * rq + 1]),
                                                cc[4 * rq + 2]), cc[4 * rq + 3]), 0.f);
                    wb[1536 * t9 + 96 * rq] = f2fp8(p);
                }
            }
        }

        // pack prefetched image into the other buffer
        if (pf) {
            unsigned short* dst = (unsigned short*)((char*)simgb + (SOFF ^ 3136));
            *(u32x4*)(&dst[8 * tid]) =
                (u32x4){pk2(A4.x, A4.y), pk2(A4.z, A4.w), pk2(B4.x, B4.y), pk2(B4.z, B4.w)};
            *(u32x4*)(&dst[784 + 8 * tid]) =
                (u32x4){pk2(A4.y, A4.z), pk2(A4.w, B4.x), pk2(B4.y, B4.z), pk2(B4.w, sc)};
        }
        asm volatile("s_waitcnt lgkmcnt(0)" ::: "memory");
        __builtin_amdgcn_s_barrier();

        // ---- conv2: M-tile wv, BOTH N-halves, 5 fp8 K=64 chunks,
        //      A from LDS once, B streamed from L1-resident w2f8 ----
        {
            const unsigned char* ab = sp2 + POFF + posq;
            f32x16 acc0, acc1;
            #pragma unroll
            for (int z = 0; z < 16; ++z) { acc0[z] = cb20; acc1[z] = cb21; }
#define C2STEP(OC, CI)                                                          \
            {                                                                   \
                const i32x8 bf0 = *(const i32x8*)(w2f8 + bgo + 4096 * (CI));    \
                const i32x8 bf1 = *(const i32x8*)(w2f8 + bgo + 4096 * (CI) + 1024); \
                u32x4 r0 = *(const u32x4*)(ab + (OC));                          \
                u32x4 r1 = *(const u32x4*)(ab + (OC) + 16);                     \
                i32x8 af8 = __builtin_bit_cast(i32x8,                           \
                    __builtin_shufflevector(r0, r1, 0, 1, 2, 3, 4, 5, 6, 7));   \
                acc0 = __builtin_amdgcn_mfma_scale_f32_32x32x64_f8f6f4(         \
                    af8, bf0, acc0, 0, 0, 0, 127, 0, 127);                      \
                acc1 = __builtin_amdgcn_mfma_scale_f32_32x32x64_f8f6f4(         \
                    af8, bf1, acc1, 0, 0, 0, 127, 0, 127);                      \
            }
            C2STEP(o0, 0)
            C2STEP(o1, 1)
            C2STEP(o2, 2)
            C2STEP(o3, 3)
            C2STEP(o4, 4)
#undef C2STEP
            #pragma unroll
            for (int rq = 0; rq < 4; ++rq) {
                float p0 = fmaxf(fmaxf(fmaxf(fmaxf(acc0[4 * rq], acc0[4 * rq + 1]),
                                             acc0[4 * rq + 2]), acc0[4 * rq + 3]), 0.f);
                float p1 = fmaxf(fmaxf(fmaxf(fmaxf(acc1[4 * rq], acc1[4 * rq + 1]),
                                             acc1[4 * rq + 2]), acc1[4 * rq + 3]), 0.f);
                pacc0[rq] += p0;
                pacc1[rq] += p1;
            }
        }
    }

    // one atomic per (quad, channel) per block; wv==3 keeps only rq0/lh0 (q2==24)
    const int grp = imgbase >> 9;
    float* gs = gsum + grp * EMB;
    #pragma unroll
    for (int rq = 0; rq < 4; ++rq) {
        if (wv < 3 || (rq == 0 && lh == 0)) {
            const int q2 = 8 * wv + 2 * rq + lh;
            atomicAdd(&gs[q2 * 64 + l31],      pacc0[rq]);
            atomicAdd(&gs[q2 * 64 + 32 + l31], pacc1[rq]);
        }
    }
}

// mean/512 -> max over 16 groups -> dot v -> + fc1b.fc2w + fc2b -> sigmoid
__global__ __launch_bounds__(256) void head(
        const float* __restrict__ gsum, const float* __restrict__ v,
        const float* __restrict__ fc1b, const float* __restrict__ fc2w,
        const float* __restrict__ fc2b, float* __restrict__ out)
{
    __shared__ float sred[256];
    const int tid = threadIdx.x;
    float partial = 0.f;
    const float4* g4 = (const float4*)gsum;
    const float4* v4 = (const float4*)v;
    for (int i = tid; i < 400; i += 256) {
        float4 m = g4[i];
        #pragma unroll
        for (int gg = 1; gg < GROUPS; ++gg) {
            float4 t = g4[gg * 400 + i];
            m.x = fmaxf(m.x, t.x); m.y = fmaxf(m.y, t.y);
            m.z = fmaxf(m.z, t.z); m.w = fmaxf(m.w, t.w);
        }
        float4 vv = v4[i];
        partial += m.x * vv.x + m.y * vv.y + m.z * vv.z + m.w * vv.w;
    }
    partial *= (1.f / 512.f);
    partial += fc1b[tid] * fc2w[tid] + fc1b[tid + 256] * fc2w[tid + 256];
    sred[tid] = partial;
    __syncthreads();
    for (int s = 128; s > 0; s >>= 1) {
        if (tid < s) sred[tid] += sred[tid + s];
        __syncthreads();
    }
    if (tid == 0) out[0] = 1.f / (1.f + expf(-(sred[0] + fc2b[0])));
}

extern "C" void kernel_launch(void* const* d_in, const int* in_sizes, int n_in,
                              void* d_out, int out_size, void* d_ws, size_t ws_size,
                              hipStream_t stream)
{
    const float* x    = (const float*)d_in[0];
    const float* w1   = (const float*)d_in[1];
    const float* b1   = (const float*)d_in[2];
    const float* w2   = (const float*)d_in[3];
    const float* b2   = (const float*)d_in[4];
    const float* fc1w = (const float*)d_in[5];
    const float* fc1b = (const float*)d_in[6];
    const float* fc2w = (const float*)d_in[7];
    const float* fc2b = (const float*)d_in[8];

    float* gsum = (float*)d_ws;
    unsigned char* w2f8 = (unsigned char*)d_ws + WS_W2F8;
    unsigned short* w1f = (unsigned short*)((char*)d_ws + WS_W1F);
    float* v = (float*)((char*)d_ws + WS_V);

    prep<<<582, 256, 0, stream>>>(w1, w2, fc1w, fc2w, gsum, w1f, w2f8, v);
    fused<<<N_IMG / IPB, 256, 0, stream>>>(x, w1f, b1, w2f8, b2, gsum);
    head<<<1, 256, 0, stream>>>(gsum, v, fc1b, fc2w, fc2b, (float*)d_out);
}

// Round 16
// 54.573 us; speedup vs baseline: 1.8702x; 1.8702x over previous
//
#include <hip/hip_runtime.h>
#include <hip/hip_bf16.h>
#include <math.h>

#define N_IMG 8192
#define GROUPS 16
#define EMB 1600
#define IPB 4            // 2048 blocks -> 5 resident blocks/CU (88 VGPR class)

typedef __attribute__((ext_vector_type(8))) short short8;
typedef __attribute__((ext_vector_type(16))) float f32x16;
typedef __attribute__((ext_vector_type(4))) unsigned int u32x4;
typedef __attribute__((ext_vector_type(8))) int i32x8;

// ws layout (bytes): gsum[25600 f32]@0 ; w2f8[20480 u8]@102400 ;
//                    w1f[512 bf16]@122880 ; v[1600 f32]@123904
#define WS_W2F8 102400
#define WS_W1F  122880
#define WS_V    123904

__device__ __forceinline__ unsigned short bfc(float f) {
    return __builtin_bit_cast(unsigned short, __float2bfloat16(f));
}
__device__ __forceinline__ unsigned pk2(float a, float b) {
    return (unsigned)bfc(a) | ((unsigned)bfc(b) << 16);
}
__device__ __forceinline__ unsigned char f2fp8(float f) {
    return (unsigned char)(__builtin_amdgcn_cvt_pk_fp8_f32(f, f, 0, false) & 0xFF);
}

// ---------------------------------------------------------------------------
// prep: zero gsum [0,25600) ; pack w2 -> fp8 frag order [25600,46080) ;
// pack w1 bf16 frags [46080,46592) ; v = fc1w @ fc2w with one WAVE per
// output d (coalesced row reads + butterfly reduce) [46592,148992).
// ---------------------------------------------------------------------------
__global__ __launch_bounds__(256) void prep(
        const float* __restrict__ w1, const float* __restrict__ w2,
        const float* __restrict__ fc1w, const float* __restrict__ fc2w,
        float* __restrict__ gsum, unsigned short* __restrict__ w1f,
        unsigned char* __restrict__ w2f8, float* __restrict__ v)
{
    int gid = blockIdx.x * 256 + threadIdx.x;
    if (gid < 25600) { gsum[gid] = 0.f; return; }
    if (gid < 46080) {
        int i = gid - 25600;
        int u = i & 31, n = (i >> 5) & 63, t = i >> 11;
        unsigned char q = 0;
        if (t < 9) q = f2fp8(w2[(t * 32 + u) * 64 + n]);
        w2f8[i] = q;
        return;
    }
    if (gid < 46592) {
        int i = gid - 46080;
        int j = i & 7, ll = i >> 3;
        int k = 8 * (ll >> 5) + j;
        int r = k >> 2, c4 = k & 3, co = ll & 31;
        w1f[i] = (r < 3 && c4 < 3) ? bfc(w1[(r * 3 + c4) * 32 + co])
                                   : (unsigned short)0;
        return;
    }
    {
        const int d = (gid - 46592) >> 6;
        if (d < 1600) {
            const int lane = gid & 63;
            const float4* a = (const float4*)(fc1w + d * 512 + lane * 8);
            const float4* b = (const float4*)(fc2w + lane * 8);
            const float4 a0 = a[0], a1 = a[1], b0 = b[0], b1 = b[1];
            float s = a0.x * b0.x + a0.y * b0.y + a0.z * b0.z + a0.w * b0.w
                    + a1.x * b1.x + a1.y * b1.y + a1.z * b1.z + a1.w * b1.w;
            #pragma unroll
            for (int off = 32; off; off >>= 1) s += __shfl_xor(s, off);
            if (lane == 0) v[d] = s;
        }
    }
}

// ---------------------------------------------------------------------------
// Fused (R11 hot loop byte-identical; only IPB=4 + forced-rolled image loop):
// 4 waves/block (2M x 2N), bf16 32x32x16 conv1 + fp8 mfma_scale 32x32x64
// conv2 (K=288 in 5 K=64 chunks, tap = 2*chunk + lh, tap 9 zero-weight pad),
// sp2 = fp8 [144 pos][48B], 1 raw s_barrier per image (buffer parity),
// register prefetch of next image. #pragma unroll 1 keeps the loop rolled
// (R13's IPB=4 full-unroll blew VGPR 88 -> 200).
// ---------------------------------------------------------------------------
__global__ __launch_bounds__(256) void fused(
        const float* __restrict__ x,
        const unsigned short* __restrict__ w1f, const float* __restrict__ b1,
        const unsigned char* __restrict__ w2f8, const float* __restrict__ b2,
        float* __restrict__ gsum)
{
    __shared__ __align__(16) unsigned short simgb[2 * 1568];  // [dbuf][copy0|copy1]
    __shared__ __align__(16) unsigned char sp2[2 * 6912];     // [dbuf][144 pos][48B]

    const int tid = threadIdx.x;
    const int wv = tid >> 6;
    const int l = tid & 63;
    const int l31 = l & 31, lh = l >> 5;
    const int mw = wv & 1, nw = wv >> 1;

    // conv1 B-frag
    const short8 wb1 = *(const short8*)(w1f + l * 8);
    const float cb1 = b1[l31];

    // conv2 B-frags: fp8, one N-half, 5 K=64 chunks (40 VGPR)
    i32x8 bb[5];
    #pragma unroll
    for (int c = 0; c < 5; ++c)
        bb[c] = *(const i32x8*)(w2f8 + ((2 * c + lh) * 64 + 32 * nw + l31) * 32);
    const float cb2 = b2[32 * nw + l31];

    // ---- lane-invariant integer BYTE offsets ----
    const int rb_inv = 2 * ((l & 1) * 784 + ((l >> 1) & 1) * 28 + 56 * lh);
    const int wb_inv = 384 * wv + 48 * lh + l31;        // conv1 fp8 write base
    const int ew = 8 * wv + (l31 >> 2);
    int posq0, posq1;
    {
        int m2 = 32 * mw + l31;
        int q2i = m2 >> 2, idx2 = m2 & 3;
        posq0 = ((2 * (q2i / 5) + (idx2 >> 1)) * 12 + 2 * (q2i % 5) + (idx2 & 1)) * 48;
        m2 = 32 * (2 + mw) + l31; if (m2 > 99) m2 = 99;
        q2i = m2 >> 2; idx2 = m2 & 3;
        posq1 = ((2 * (q2i / 5) + (idx2 >> 1)) * 12 + 2 * (q2i % 5) + (idx2 & 1)) * 48;
    }
    // chunk tap row offsets: tap = 2c+lh, shift(t) = ((t/3)*12 + t%3)*48
    const int o0 = lh ? 48   : 0;
    const int o1 = lh ? 576  : 96;
    const int o2 = lh ? 672  : 624;
    const int o3 = lh ? 1200 : 1152;
    const int o4 = lh ? 0    : 1248;   // tap 9 (zero weights) reads base row

    float pacc[2][4];
    #pragma unroll
    for (int a = 0; a < 2; ++a)
        #pragma unroll
        for (int b = 0; b < 4; ++b) pacc[a][b] = 0.f;

    const int imgbase = blockIdx.x * IPB;
    const float* xbase = x + (size_t)imgbase * 784;

    // prologue: pack image 0 into buffer 0 (copy0 + 1-px-shifted copy1)
    if (tid < 98) {
        const float4* xg = (const float4*)xbase;
        float4 A = xg[2 * tid], B = xg[2 * tid + 1];
        float sc = xbase[(8 * tid + 8 < 784) ? 8 * tid + 8 : 783];
        *(u32x4*)(&simgb[8 * tid]) =
            (u32x4){pk2(A.x, A.y), pk2(A.z, A.w), pk2(B.x, B.y), pk2(B.z, B.w)};
        *(u32x4*)(&simgb[784 + 8 * tid]) =
            (u32x4){pk2(A.y, A.z), pk2(A.w, B.x), pk2(B.y, B.z), pk2(B.w, sc)};
    }
    asm volatile("s_waitcnt lgkmcnt(0)" ::: "memory");
    __builtin_amdgcn_s_barrier();

    #pragma unroll 1
    for (int ii = 0; ii < IPB; ++ii) {
        const int SOFF = (ii & 1) * 3136;   // simgb dbuf BYTE offset
        const int POFF = (ii & 1) * 6912;   // sp2 dbuf BYTE offset
        const char* rb = (const char*)simgb + (SOFF + rb_inv);
        unsigned char* wb = sp2 + (POFF + wb_inv);

        // issue next-image global loads early
        float4 A4, B4; float sc = 0.f;
        const bool pf = (ii + 1 < IPB) && (tid < 98);
        if (pf) {
            const float4* xn = (const float4*)(xbase + (ii + 1) * 784);
            A4 = xn[2 * tid]; B4 = xn[2 * tid + 1];
            sc = xbase[(ii + 1) * 784 + ((8 * tid + 8 < 784) ? 8 * tid + 8 : 783)];
        }

        // ---- conv1: tiles t = 4*t9 + wv (bf16 MFMA), fp8 pooled writes ----
        #pragma unroll
        for (int t9 = 0; t9 < 5; ++t9) {
            if (4 * t9 + wv < 18) {
                const int qd = 32 * t9 + ew;
                const int pr = qd / 12, pc = qd - 12 * pr;
                const unsigned* bp = (const unsigned*)(rb + (112 * pr + 4 * pc));
                const unsigned d0 = bp[0], d1 = bp[1], d2 = bp[14], d3 = bp[15];
                const short8 af = __builtin_bit_cast(short8, (u32x4){d0, d1, d2, d3});
                f32x16 cc;
                #pragma unroll
                for (int z = 0; z < 16; ++z) cc[z] = cb1;
                cc = __builtin_amdgcn_mfma_f32_32x32x16_bf16(af, wb1, cc, 0, 0, 0);
                #pragma unroll
                for (int rq = 0; rq < 4; ++rq) {
                    float p = fmaxf(fmaxf(fmaxf(fmaxf(cc[4 * rq], cc[4 * rq + 1]),
                                                cc[4 * rq + 2]), cc[4 * rq + 3]), 0.f);
                    wb[1536 * t9 + 96 * rq] = f2fp8(p);
                }
            }
        }

        // pack prefetched image into the other buffer
        if (pf) {
            unsigned short* dst = (unsigned short*)((char*)simgb + (SOFF ^ 3136));
            *(u32x4*)(&dst[8 * tid]) =
                (u32x4){pk2(A4.x, A4.y), pk2(A4.z, A4.w), pk2(B4.x, B4.y), pk2(B4.z, B4.w)};
            *(u32x4*)(&dst[784 + 8 * tid]) =
                (u32x4){pk2(A4.y, A4.z), pk2(A4.w, B4.x), pk2(B4.y, B4.z), pk2(B4.w, sc)};
        }
        asm volatile("s_waitcnt lgkmcnt(0)" ::: "memory");
        __builtin_amdgcn_s_barrier();

        // ---- conv2: 2 M-tiles, one N-half, 5 fp8 K=64 chunks each ----
        #pragma unroll
        for (int mti = 0; mti < 2; ++mti) {
            const unsigned char* ab = sp2 + POFF + (mti ? posq1 : posq0);
            f32x16 acc;
            #pragma unroll
            for (int z = 0; z < 16; ++z) acc[z] = cb2;
#define C2STEP(OC, CI)                                                          \
            {                                                                   \
                u32x4 r0 = *(const u32x4*)(ab + (OC));                          \
                u32x4 r1 = *(const u32x4*)(ab + (OC) + 16);                     \
                i32x8 af8 = __builtin_bit_cast(i32x8,                           \
                    __builtin_shufflevector(r0, r1, 0, 1, 2, 3, 4, 5, 6, 7));   \
                acc = __builtin_amdgcn_mfma_scale_f32_32x32x64_f8f6f4(          \
                    af8, bb[CI], acc, 0, 0, 0, 127, 0, 127);                    \
            }
            C2STEP(o0, 0)
            C2STEP(o1, 1)
            C2STEP(o2, 2)
            C2STEP(o3, 3)
            C2STEP(o4, 4)
#undef C2STEP
            #pragma unroll
            for (int rq = 0; rq < 4; ++rq) {
                float p = fmaxf(fmaxf(fmaxf(fmaxf(acc[4 * rq], acc[4 * rq + 1]),
                                            acc[4 * rq + 2]), acc[4 * rq + 3]), 0.f);
                pacc[mti][rq] += p;
            }
        }
    }

    // one atomic per (quad, channel) per block; mt==3 keeps only rq0/lh0 (q2==24)
    const int grp = imgbase >> 9;
    float* gs = gsum + grp * EMB;
    #pragma unroll
    for (int mti = 0; mti < 2; ++mti) {
        const int mt = 2 * mti + mw;
        #pragma unroll
        for (int rq = 0; rq < 4; ++rq) {
            if (mt < 3 || (rq == 0 && lh == 0)) {
                const int q2 = 8 * mt + 2 * rq + lh;
                atomicAdd(&gs[q2 * 64 + 32 * nw + l31], pacc[mti][rq]);
            }
        }
    }
}

// mean/512 -> max over 16 groups -> dot v -> + fc1b.fc2w + fc2b -> sigmoid
__global__ __launch_bounds__(256) void head(
        const float* __restrict__ gsum, const float* __restrict__ v,
        const float* __restrict__ fc1b, const float* __restrict__ fc2w,
        const float* __restrict__ fc2b, float* __restrict__ out)
{
    __shared__ float sred[256];
    const int tid = threadIdx.x;
    float partial = 0.f;
    const float4* g4 = (const float4*)gsum;
    const float4* v4 = (const float4*)v;
    for (int i = tid; i < 400; i += 256) {
        float4 m = g4[i];
        #pragma unroll
        for (int gg = 1; gg < GROUPS; ++gg) {
            float4 t = g4[gg * 400 + i];
            m.x = fmaxf(m.x, t.x); m.y = fmaxf(m.y, t.y);
            m.z = fmaxf(m.z, t.z); m.w = fmaxf(m.w, t.w);
        }
        float4 vv = v4[i];
        partial += m.x * vv.x + m.y * vv.y + m.z * vv.z + m.w * vv.w;
    }
    partial *= (1.f / 512.f);
    partial += fc1b[tid] * fc2w[tid] + fc1b[tid + 256] * fc2w[tid + 256];
    sred[tid] = partial;
    __syncthreads();
    for (int s = 128; s > 0; s >>= 1) {
        if (tid < s) sred[tid] += sred[tid + s];
        __syncthreads();
    }
    if (tid == 0) out[0] = 1.f / (1.f + expf(-(sred[0] + fc2b[0])));
}

extern "C" void kernel_launch(void* const* d_in, const int* in_sizes, int n_in,
                              void* d_out, int out_size, void* d_ws, size_t ws_size,
                              hipStream_t stream)
{
    const float* x    = (const float*)d_in[0];
    const float* w1   = (const float*)d_in[1];
    const float* b1   = (const float*)d_in[2];
    const float* w2   = (const float*)d_in[3];
    const float* b2   = (const float*)d_in[4];
    const float* fc1w = (const float*)d_in[5];
    const float* fc1b = (const float*)d_in[6];
    const float* fc2w = (const float*)d_in[7];
    const float* fc2b = (const float*)d_in[8];

    float* gsum = (float*)d_ws;
    unsigned char* w2f8 = (unsigned char*)d_ws + WS_W2F8;
    unsigned short* w1f = (unsigned short*)((char*)d_ws + WS_W1F);
    float* v = (float*)((char*)d_ws + WS_V);

    prep<<<582, 256, 0, stream>>>(w1, w2, fc1w, fc2w, gsum, w1f, w2f8, v);
    fused<<<N_IMG / IPB, 256, 0, stream>>>(x, w1f, b1, w2f8, b2, gsum);
    head<<<1, 256, 0, stream>>>(gsum, v, fc1b, fc2w, fc2b, (float*)d_out);
}

// Round 17
// 47.633 us; speedup vs baseline: 2.1427x; 1.1457x over previous
//
#include <hip/hip_runtime.h>
#include <hip/hip_bf16.h>
#include <math.h>

#define N_IMG 8192
#define GROUPS 16
#define EMB 1600
#define IPB 8            // 1024 blocks; best measured fused config (R11: 43.3us)

typedef __attribute__((ext_vector_type(8))) short short8;
typedef __attribute__((ext_vector_type(16))) float f32x16;
typedef __attribute__((ext_vector_type(4))) unsigned int u32x4;
typedef __attribute__((ext_vector_type(8))) int i32x8;

// ws layout (bytes): gsum[25600 f32]@0 ; w2f8[20480 u8]@102400 ;
//                    w1f[512 bf16]@122880 ; v[1600 f32]@123904
#define WS_W2F8 102400
#define WS_W1F  122880
#define WS_V    123904

__device__ __forceinline__ unsigned short bfc(float f) {
    return __builtin_bit_cast(unsigned short, __float2bfloat16(f));
}
__device__ __forceinline__ unsigned pk2(float a, float b) {
    return (unsigned)bfc(a) | ((unsigned)bfc(b) << 16);
}
__device__ __forceinline__ unsigned char f2fp8(float f) {
    return (unsigned char)(__builtin_amdgcn_cvt_pk_fp8_f32(f, f, 0, false) & 0xFF);
}

// ---------------------------------------------------------------------------
// prep: zero gsum [0,25600) ; pack w2 -> fp8 frag order [25600,46080) ;
// pack w1 bf16 frags [46080,46592) ; v = fc1w @ fc2w with one WAVE per
// output d (coalesced row reads + butterfly reduce) [46592,148992).
// ---------------------------------------------------------------------------
__global__ __launch_bounds__(256) void prep(
        const float* __restrict__ w1, const float* __restrict__ w2,
        const float* __restrict__ fc1w, const float* __restrict__ fc2w,
        float* __restrict__ gsum, unsigned short* __restrict__ w1f,
        unsigned char* __restrict__ w2f8, float* __restrict__ v)
{
    int gid = blockIdx.x * 256 + threadIdx.x;
    if (gid < 25600) { gsum[gid] = 0.f; return; }
    if (gid < 46080) {
        int i = gid - 25600;
        int u = i & 31, n = (i >> 5) & 63, t = i >> 11;
        unsigned char q = 0;
        if (t < 9) q = f2fp8(w2[(t * 32 + u) * 64 + n]);
        w2f8[i] = q;
        return;
    }
    if (gid < 46592) {
        int i = gid - 46080;
        int j = i & 7, ll = i >> 3;
        int k = 8 * (ll >> 5) + j;
        int r = k >> 2, c4 = k & 3, co = ll & 31;
        w1f[i] = (r < 3 && c4 < 3) ? bfc(w1[(r * 3 + c4) * 32 + co])
                                   : (unsigned short)0;
        return;
    }
    {
        const int d = (gid - 46592) >> 6;
        if (d < 1600) {
            const int lane = gid & 63;
            const float4* a = (const float4*)(fc1w + d * 512 + lane * 8);
            const float4* b = (const float4*)(fc2w + lane * 8);
            const float4 a0 = a[0], a1 = a[1], b0 = b[0], b1 = b[1];
            float s = a0.x * b0.x + a0.y * b0.y + a0.z * b0.z + a0.w * b0.w
                    + a1.x * b1.x + a1.y * b1.y + a1.z * b1.z + a1.w * b1.w;
            #pragma unroll
            for (int off = 32; off; off >>= 1) s += __shfl_xor(s, off);
            if (lane == 0) v[d] = s;
        }
    }
}

// ---------------------------------------------------------------------------
// Fused (R11 hot loop byte-identical): 4 waves/block (2M x 2N), IPB=8 images,
// bf16 32x32x16 conv1 (dual shifted image copies, uniform reads) + fp8 e4m3
// mfma_scale 32x32x64 conv2 (K=288 in 5 K=64 chunks, tap = 2*chunk + lh,
// tap 9 zero-weight pad), sp2 = fp8 [144 pos][48B], 1 raw s_barrier/image
// (buffer parity), register prefetch of next image. #pragma unroll 1 pins
// the rolled image loop (full unroll inflates VGPR 88 -> 200, R13).
// ---------------------------------------------------------------------------
__global__ __launch_bounds__(256) void fused(
        const float* __restrict__ x,
        const unsigned short* __restrict__ w1f, const float* __restrict__ b1,
        const unsigned char* __restrict__ w2f8, const float* __restrict__ b2,
        float* __restrict__ gsum)
{
    __shared__ __align__(16) unsigned short simgb[2 * 1568];  // [dbuf][copy0|copy1]
    __shared__ __align__(16) unsigned char sp2[2 * 6912];     // [dbuf][144 pos][48B]

    const int tid = threadIdx.x;
    const int wv = tid >> 6;
    const int l = tid & 63;
    const int l31 = l & 31, lh = l >> 5;
    const int mw = wv & 1, nw = wv >> 1;

    // conv1 B-frag
    const short8 wb1 = *(const short8*)(w1f + l * 8);
    const float cb1 = b1[l31];

    // conv2 B-frags: fp8, one N-half, 5 K=64 chunks (40 VGPR)
    i32x8 bb[5];
    #pragma unroll
    for (int c = 0; c < 5; ++c)
        bb[c] = *(const i32x8*)(w2f8 + ((2 * c + lh) * 64 + 32 * nw + l31) * 32);
    const float cb2 = b2[32 * nw + l31];

    // ---- lane-invariant integer BYTE offsets ----
    const int rb_inv = 2 * ((l & 1) * 784 + ((l >> 1) & 1) * 28 + 56 * lh);
    const int wb_inv = 384 * wv + 48 * lh + l31;        // conv1 fp8 write base
    const int ew = 8 * wv + (l31 >> 2);
    int posq0, posq1;
    {
        int m2 = 32 * mw + l31;
        int q2i = m2 >> 2, idx2 = m2 & 3;
        posq0 = ((2 * (q2i / 5) + (idx2 >> 1)) * 12 + 2 * (q2i % 5) + (idx2 & 1)) * 48;
        m2 = 32 * (2 + mw) + l31; if (m2 > 99) m2 = 99;
        q2i = m2 >> 2; idx2 = m2 & 3;
        posq1 = ((2 * (q2i / 5) + (idx2 >> 1)) * 12 + 2 * (q2i % 5) + (idx2 & 1)) * 48;
    }
    // chunk tap row offsets: tap = 2c+lh, shift(t) = ((t/3)*12 + t%3)*48
    const int o0 = lh ? 48   : 0;
    const int o1 = lh ? 576  : 96;
    const int o2 = lh ? 672  : 624;
    const int o3 = lh ? 1200 : 1152;
    const int o4 = lh ? 0    : 1248;   // tap 9 (zero weights) reads base row

    float pacc[2][4];
    #pragma unroll
    for (int a = 0; a < 2; ++a)
        #pragma unroll
        for (int b = 0; b < 4; ++b) pacc[a][b] = 0.f;

    const int imgbase = blockIdx.x * IPB;
    const float* xbase = x + (size_t)imgbase * 784;

    // prologue: pack image 0 into buffer 0 (copy0 + 1-px-shifted copy1)
    if (tid < 98) {
        const float4* xg = (const float4*)xbase;
        float4 A = xg[2 * tid], B = xg[2 * tid + 1];
        float sc = xbase[(8 * tid + 8 < 784) ? 8 * tid + 8 : 783];
        *(u32x4*)(&simgb[8 * tid]) =
            (u32x4){pk2(A.x, A.y), pk2(A.z, A.w), pk2(B.x, B.y), pk2(B.z, B.w)};
        *(u32x4*)(&simgb[784 + 8 * tid]) =
            (u32x4){pk2(A.y, A.z), pk2(A.w, B.x), pk2(B.y, B.z), pk2(B.w, sc)};
    }
    asm volatile("s_waitcnt lgkmcnt(0)" ::: "memory");
    __builtin_amdgcn_s_barrier();

    #pragma unroll 1
    for (int ii = 0; ii < IPB; ++ii) {
        const int SOFF = (ii & 1) * 3136;   // simgb dbuf BYTE offset
        const int POFF = (ii & 1) * 6912;   // sp2 dbuf BYTE offset
        const char* rb = (const char*)simgb + (SOFF + rb_inv);
        unsigned char* wb = sp2 + (POFF + wb_inv);

        // issue next-image global loads early
        float4 A4, B4; float sc = 0.f;
        const bool pf = (ii + 1 < IPB) && (tid < 98);
        if (pf) {
            const float4* xn = (const float4*)(xbase + (ii + 1) * 784);
            A4 = xn[2 * tid]; B4 = xn[2 * tid + 1];
            sc = xbase[(ii + 1) * 784 + ((8 * tid + 8 < 784) ? 8 * tid + 8 : 783)];
        }

        // ---- conv1: tiles t = 4*t9 + wv (bf16 MFMA), fp8 pooled writes ----
        #pragma unroll
        for (int t9 = 0; t9 < 5; ++t9) {
            if (4 * t9 + wv < 18) {
                const int qd = 32 * t9 + ew;
                const int pr = qd / 12, pc = qd - 12 * pr;
                const unsigned* bp = (const unsigned*)(rb + (112 * pr + 4 * pc));
                const unsigned d0 = bp[0], d1 = bp[1], d2 = bp[14], d3 = bp[15];
                const short8 af = __builtin_bit_cast(short8, (u32x4){d0, d1, d2, d3});
                f32x16 cc;
                #pragma unroll
                for (int z = 0; z < 16; ++z) cc[z] = cb1;
                cc = __builtin_amdgcn_mfma_f32_32x32x16_bf16(af, wb1, cc, 0, 0, 0);
                #pragma unroll
                for (int rq = 0; rq < 4; ++rq) {
                    float p = fmaxf(fmaxf(fmaxf(fmaxf(cc[4 * rq], cc[4 * rq + 1]),
                                                cc[4 * rq + 2]), cc[4 * rq + 3]), 0.f);
                    wb[1536 * t9 + 96 * rq] = f2fp8(p);
                }
            }
        }

        // pack prefetched image into the other buffer
        if (pf) {
            unsigned short* dst = (unsigned short*)((char*)simgb + (SOFF ^ 3136));
            *(u32x4*)(&dst[8 * tid]) =
                (u32x4){pk2(A4.x, A4.y), pk2(A4.z, A4.w), pk2(B4.x, B4.y), pk2(B4.z, B4.w)};
            *(u32x4*)(&dst[784 + 8 * tid]) =
                (u32x4){pk2(A4.y, A4.z), pk2(A4.w, B4.x), pk2(B4.y, B4.z), pk2(B4.w, sc)};
        }
        asm volatile("s_waitcnt lgkmcnt(0)" ::: "memory");
        __builtin_amdgcn_s_barrier();

        // ---- conv2: 2 M-tiles, one N-half, 5 fp8 K=64 chunks each ----
        #pragma unroll
        for (int mti = 0; mti < 2; ++mti) {
            const unsigned char* ab = sp2 + POFF + (mti ? posq1 : posq0);
            f32x16 acc;
            #pragma unroll
            for (int z = 0; z < 16; ++z) acc[z] = cb2;
#define C2STEP(OC, CI)                                                          \
            {                                                                   \
                u32x4 r0 = *(const u32x4*)(ab + (OC));                          \
                u32x4 r1 = *(const u32x4*)(ab + (OC) + 16);                     \
                i32x8 af8 = __builtin_bit_cast(i32x8,                           \
                    __builtin_shufflevector(r0, r1, 0, 1, 2, 3, 4, 5, 6, 7));   \
                acc = __builtin_amdgcn_mfma_scale_f32_32x32x64_f8f6f4(          \
                    af8, bb[CI], acc, 0, 0, 0, 127, 0, 127);                    \
            }
            C2STEP(o0, 0)
            C2STEP(o1, 1)
            C2STEP(o2, 2)
            C2STEP(o3, 3)
            C2STEP(o4, 4)
#undef C2STEP
            #pragma unroll
            for (int rq = 0; rq < 4; ++rq) {
                float p = fmaxf(fmaxf(fmaxf(fmaxf(acc[4 * rq], acc[4 * rq + 1]),
                                            acc[4 * rq + 2]), acc[4 * rq + 3]), 0.f);
                pacc[mti][rq] += p;
            }
        }
    }

    // one atomic per (quad, channel) per block; mt==3 keeps only rq0/lh0 (q2==24)
    const int grp = imgbase >> 9;
    float* gs = gsum + grp * EMB;
    #pragma unroll
    for (int mti = 0; mti < 2; ++mti) {
        const int mt = 2 * mti + mw;
        #pragma unroll
        for (int rq = 0; rq < 4; ++rq) {
            if (mt < 3 || (rq == 0 && lh == 0)) {
                const int q2 = 8 * mt + 2 * rq + lh;
                atomicAdd(&gs[q2 * 64 + 32 * nw + l31], pacc[mti][rq]);
            }
        }
    }
}

// mean/512 -> max over 16 groups -> dot v -> + fc1b.fc2w + fc2b -> sigmoid
__global__ __launch_bounds__(256) void head(
        const float* __restrict__ gsum, const float* __restrict__ v,
        const float* __restrict__ fc1b, const float* __restrict__ fc2w,
        const float* __restrict__ fc2b, float* __restrict__ out)
{
    __shared__ float sred[256];
    const int tid = threadIdx.x;
    float partial = 0.f;
    const float4* g4 = (const float4*)gsum;
    const float4* v4 = (const float4*)v;
    for (int i = tid; i < 400; i += 256) {
        float4 m = g4[i];
        #pragma unroll
        for (int gg = 1; gg < GROUPS; ++gg) {
            float4 t = g4[gg * 400 + i];
            m.x = fmaxf(m.x, t.x); m.y = fmaxf(m.y, t.y);
            m.z = fmaxf(m.z, t.z); m.w = fmaxf(m.w, t.w);
        }
        float4 vv = v4[i];
        partial += m.x * vv.x + m.y * vv.y + m.z * vv.z + m.w * vv.w;
    }
    partial *= (1.f / 512.f);
    partial += fc1b[tid] * fc2w[tid] + fc1b[tid + 256] * fc2w[tid + 256];
    sred[tid] = partial;
    __syncthreads();
    for (int s = 128; s > 0; s >>= 1) {
        if (tid < s) sred[tid] += sred[tid + s];
        __syncthreads();
    }
    if (tid == 0) out[0] = 1.f / (1.f + expf(-(sred[0] + fc2b[0])));
}

extern "C" void kernel_launch(void* const* d_in, const int* in_sizes, int n_in,
                              void* d_out, int out_size, void* d_ws, size_t ws_size,
                              hipStream_t stream)
{
    const float* x    = (const float*)d_in[0];
    const float* w1   = (const float*)d_in[1];
    const float* b1   = (const float*)d_in[2];
    const float* w2   = (const float*)d_in[3];
    const float* b2   = (const float*)d_in[4];
    const float* fc1w = (const float*)d_in[5];
    const float* fc1b = (const float*)d_in[6];
    const float* fc2w = (const float*)d_in[7];
    const float* fc2b = (const float*)d_in[8];

    float* gsum = (float*)d_ws;
    unsigned char* w2f8 = (unsigned char*)d_ws + WS_W2F8;
    unsigned short* w1f = (unsigned short*)((char*)d_ws + WS_W1F);
    float* v = (float*)((char*)d_ws + WS_V);

    prep<<<582, 256, 0, stream>>>(w1, w2, fc1w, fc2w, gsum, w1f, w2f8, v);
    fused<<<N_IMG / IPB, 256, 0, stream>>>(x, w1f, b1, w2f8, b2, gsum);
    head<<<1, 256, 0, stream>>>(gsum, v, fc1b, fc2w, fc2b, (float*)d_out);
}

// Round 18
// 46.867 us; speedup vs baseline: 2.1777x; 1.0163x over previous
//
#include <hip/hip_runtime.h>
#include <hip/hip_bf16.h>
#include <math.h>

#define N_IMG 8192
#define GROUPS 16
#define EMB 1600
#define IPB 8            // 1024 blocks; best measured fused config (R11: 43.3us)

typedef __attribute__((ext_vector_type(8))) short short8;
typedef __attribute__((ext_vector_type(16))) float f32x16;
typedef __attribute__((ext_vector_type(4))) unsigned int u32x4;
typedef __attribute__((ext_vector_type(8))) int i32x8;

// ws layout (bytes): gsum[25600 f32]@0 ; w2f8[20480 u8]@102400 ;
//                    w1f[512 bf16]@122880 ; v[1600 f32]@123904
#define WS_W2F8 102400
#define WS_W1F  122880
#define WS_V    123904

__device__ __forceinline__ unsigned short bfc(float f) {
    return __builtin_bit_cast(unsigned short, __float2bfloat16(f));
}
__device__ __forceinline__ unsigned pk2(float a, float b) {
    return (unsigned)bfc(a) | ((unsigned)bfc(b) << 16);
}
__device__ __forceinline__ unsigned char f2fp8(float f) {
    return (unsigned char)(__builtin_amdgcn_cvt_pk_fp8_f32(f, f, 0, false) & 0xFF);
}

// ---------------------------------------------------------------------------
// prep: zero gsum [0,25600) ; pack w2 -> fp8 frag order [25600,46080) ;
// pack w1 bf16 frags [46080,46592) ; v = fc1w @ fc2w with one WAVE per
// output d (coalesced row reads + butterfly reduce) [46592,148992).
// ---------------------------------------------------------------------------
__global__ __launch_bounds__(256) void prep(
        const float* __restrict__ w1, const float* __restrict__ w2,
        const float* __restrict__ fc1w, const float* __restrict__ fc2w,
        float* __restrict__ gsum, unsigned short* __restrict__ w1f,
        unsigned char* __restrict__ w2f8, float* __restrict__ v)
{
    int gid = blockIdx.x * 256 + threadIdx.x;
    if (gid < 25600) { gsum[gid] = 0.f; return; }
    if (gid < 46080) {
        int i = gid - 25600;
        int u = i & 31, n = (i >> 5) & 63, t = i >> 11;
        unsigned char q = 0;
        if (t < 9) q = f2fp8(w2[(t * 32 + u) * 64 + n]);
        w2f8[i] = q;
        return;
    }
    if (gid < 46592) {
        int i = gid - 46080;
        int j = i & 7, ll = i >> 3;
        int k = 8 * (ll >> 5) + j;
        int r = k >> 2, c4 = k & 3, co = ll & 31;
        w1f[i] = (r < 3 && c4 < 3) ? bfc(w1[(r * 3 + c4) * 32 + co])
                                   : (unsigned short)0;
        return;
    }
    {
        const int d = (gid - 46592) >> 6;
        if (d < 1600) {
            const int lane = gid & 63;
            const float4* a = (const float4*)(fc1w + d * 512 + lane * 8);
            const float4* b = (const float4*)(fc2w + lane * 8);
            const float4 a0 = a[0], a1 = a[1], b0 = b[0], b1 = b[1];
            float s = a0.x * b0.x + a0.y * b0.y + a0.z * b0.z + a0.w * b0.w
                    + a1.x * b1.x + a1.y * b1.y + a1.z * b1.z + a1.w * b1.w;
            #pragma unroll
            for (int off = 32; off; off >>= 1) s += __shfl_xor(s, off);
            if (lane == 0) v[d] = s;
        }
    }
}

// ---------------------------------------------------------------------------
// Fused (R11-exact): 4 waves/block (2M x 2N), IPB=8 images, bf16 32x32x16
// conv1 (dual shifted image copies, uniform reads) + fp8 e4m3 mfma_scale
// 32x32x64 conv2 (K=288 in 5 K=64 chunks, tap = 2*chunk + lh, tap 9
// zero-weight pad), sp2 = fp8 [144 pos][48B], 1 raw s_barrier/image (buffer
// parity), register prefetch of next image. NO unroll pragma: at IPB=8 the
// compiler keeps the loop rolled (88 VGPR) AND may peel the last (pf=false)
// iteration — R17's `#pragma unroll 1` blocked that, costing ~1.3us.
// ---------------------------------------------------------------------------
__global__ __launch_bounds__(256) void fused(
        const float* __restrict__ x,
        const unsigned short* __restrict__ w1f, const float* __restrict__ b1,
        const unsigned char* __restrict__ w2f8, const float* __restrict__ b2,
        float* __restrict__ gsum)
{
    __shared__ __align__(16) unsigned short simgb[2 * 1568];  // [dbuf][copy0|copy1]
    __shared__ __align__(16) unsigned char sp2[2 * 6912];     // [dbuf][144 pos][48B]

    const int tid = threadIdx.x;
    const int wv = tid >> 6;
    const int l = tid & 63;
    const int l31 = l & 31, lh = l >> 5;
    const int mw = wv & 1, nw = wv >> 1;

    // conv1 B-frag
    const short8 wb1 = *(const short8*)(w1f + l * 8);
    const float cb1 = b1[l31];

    // conv2 B-frags: fp8, one N-half, 5 K=64 chunks (40 VGPR)
    i32x8 bb[5];
    #pragma unroll
    for (int c = 0; c < 5; ++c)
        bb[c] = *(const i32x8*)(w2f8 + ((2 * c + lh) * 64 + 32 * nw + l31) * 32);
    const float cb2 = b2[32 * nw + l31];

    // ---- lane-invariant integer BYTE offsets ----
    const int rb_inv = 2 * ((l & 1) * 784 + ((l >> 1) & 1) * 28 + 56 * lh);
    const int wb_inv = 384 * wv + 48 * lh + l31;        // conv1 fp8 write base
    const int ew = 8 * wv + (l31 >> 2);
    int posq0, posq1;
    {
        int m2 = 32 * mw + l31;
        int q2i = m2 >> 2, idx2 = m2 & 3;
        posq0 = ((2 * (q2i / 5) + (idx2 >> 1)) * 12 + 2 * (q2i % 5) + (idx2 & 1)) * 48;
        m2 = 32 * (2 + mw) + l31; if (m2 > 99) m2 = 99;
        q2i = m2 >> 2; idx2 = m2 & 3;
        posq1 = ((2 * (q2i / 5) + (idx2 >> 1)) * 12 + 2 * (q2i % 5) + (idx2 & 1)) * 48;
    }
    // chunk tap row offsets: tap = 2c+lh, shift(t) = ((t/3)*12 + t%3)*48
    const int o0 = lh ? 48   : 0;
    const int o1 = lh ? 576  : 96;
    const int o2 = lh ? 672  : 624;
    const int o3 = lh ? 1200 : 1152;
    const int o4 = lh ? 0    : 1248;   // tap 9 (zero weights) reads base row

    float pacc[2][4];
    #pragma unroll
    for (int a = 0; a < 2; ++a)
        #pragma unroll
        for (int b = 0; b < 4; ++b) pacc[a][b] = 0.f;

    const int imgbase = blockIdx.x * IPB;
    const float* xbase = x + (size_t)imgbase * 784;

    // prologue: pack image 0 into buffer 0 (copy0 + 1-px-shifted copy1)
    if (tid < 98) {
        const float4* xg = (const float4*)xbase;
        float4 A = xg[2 * tid], B = xg[2 * tid + 1];
        float sc = xbase[(8 * tid + 8 < 784) ? 8 * tid + 8 : 783];
        *(u32x4*)(&simgb[8 * tid]) =
            (u32x4){pk2(A.x, A.y), pk2(A.z, A.w), pk2(B.x, B.y), pk2(B.z, B.w)};
        *(u32x4*)(&simgb[784 + 8 * tid]) =
            (u32x4){pk2(A.y, A.z), pk2(A.w, B.x), pk2(B.y, B.z), pk2(B.w, sc)};
    }
    asm volatile("s_waitcnt lgkmcnt(0)" ::: "memory");
    __builtin_amdgcn_s_barrier();

    for (int ii = 0; ii < IPB; ++ii) {
        const int SOFF = (ii & 1) * 3136;   // simgb dbuf BYTE offset
        const int POFF = (ii & 1) * 6912;   // sp2 dbuf BYTE offset
        const char* rb = (const char*)simgb + (SOFF + rb_inv);
        unsigned char* wb = sp2 + (POFF + wb_inv);

        // issue next-image global loads early
        float4 A4, B4; float sc = 0.f;
        const bool pf = (ii + 1 < IPB) && (tid < 98);
        if (pf) {
            const float4* xn = (const float4*)(xbase + (ii + 1) * 784);
            A4 = xn[2 * tid]; B4 = xn[2 * tid + 1];
            sc = xbase[(ii + 1) * 784 + ((8 * tid + 8 < 784) ? 8 * tid + 8 : 783)];
        }

        // ---- conv1: tiles t = 4*t9 + wv (bf16 MFMA), fp8 pooled writes ----
        #pragma unroll
        for (int t9 = 0; t9 < 5; ++t9) {
            if (4 * t9 + wv < 18) {
                const int qd = 32 * t9 + ew;
                const int pr = qd / 12, pc = qd - 12 * pr;
                const unsigned* bp = (const unsigned*)(rb + (112 * pr + 4 * pc));
                const unsigned d0 = bp[0], d1 = bp[1], d2 = bp[14], d3 = bp[15];
                const short8 af = __builtin_bit_cast(short8, (u32x4){d0, d1, d2, d3});
                f32x16 cc;
                #pragma unroll
                for (int z = 0; z < 16; ++z) cc[z] = cb1;
                cc = __builtin_amdgcn_mfma_f32_32x32x16_bf16(af, wb1, cc, 0, 0, 0);
                #pragma unroll
                for (int rq = 0; rq < 4; ++rq) {
                    float p = fmaxf(fmaxf(fmaxf(fmaxf(cc[4 * rq], cc[4 * rq + 1]),
                                                cc[4 * rq + 2]), cc[4 * rq + 3]), 0.f);
                    wb[1536 * t9 + 96 * rq] = f2fp8(p);
                }
            }
        }

        // pack prefetched image into the other buffer
        if (pf) {
            unsigned short* dst = (unsigned short*)((char*)simgb + (SOFF ^ 3136));
            *(u32x4*)(&dst[8 * tid]) =
                (u32x4){pk2(A4.x, A4.y), pk2(A4.z, A4.w), pk2(B4.x, B4.y), pk2(B4.z, B4.w)};
            *(u32x4*)(&dst[784 + 8 * tid]) =
                (u32x4){pk2(A4.y, A4.z), pk2(A4.w, B4.x), pk2(B4.y, B4.z), pk2(B4.w, sc)};
        }
        asm volatile("s_waitcnt lgkmcnt(0)" ::: "memory");
        __builtin_amdgcn_s_barrier();

        // ---- conv2: 2 M-tiles, one N-half, 5 fp8 K=64 chunks each ----
        #pragma unroll
        for (int mti = 0; mti < 2; ++mti) {
            const unsigned char* ab = sp2 + POFF + (mti ? posq1 : posq0);
            f32x16 acc;
            #pragma unroll
            for (int z = 0; z < 16; ++z) acc[z] = cb2;
#define C2STEP(OC, CI)                                                          \
            {                                                                   \
                u32x4 r0 = *(const u32x4*)(ab + (OC));                          \
                u32x4 r1 = *(const u32x4*)(ab + (OC) + 16);                     \
                i32x8 af8 = __builtin_bit_cast(i32x8,                           \
                    __builtin_shufflevector(r0, r1, 0, 1, 2, 3, 4, 5, 6, 7));   \
                acc = __builtin_amdgcn_mfma_scale_f32_32x32x64_f8f6f4(          \
                    af8, bb[CI], acc, 0, 0, 0, 127, 0, 127);                    \
            }
            C2STEP(o0, 0)
            C2STEP(o1, 1)
            C2STEP(o2, 2)
            C2STEP(o3, 3)
            C2STEP(o4, 4)
#undef C2STEP
            #pragma unroll
            for (int rq = 0; rq < 4; ++rq) {
                float p = fmaxf(fmaxf(fmaxf(fmaxf(acc[4 * rq], acc[4 * rq + 1]),
                                            acc[4 * rq + 2]), acc[4 * rq + 3]), 0.f);
                pacc[mti][rq] += p;
            }
        }
    }

    // one atomic per (quad, channel) per block; mt==3 keeps only rq0/lh0 (q2==24)
    const int grp = imgbase >> 9;
    float* gs = gsum + grp * EMB;
    #pragma unroll
    for (int mti = 0; mti < 2; ++mti) {
        const int mt = 2 * mti + mw;
        #pragma unroll
        for (int rq = 0; rq < 4; ++rq) {
            if (mt < 3 || (rq == 0 && lh == 0)) {
                const int q2 = 8 * mt + 2 * rq + lh;
                atomicAdd(&gs[q2 * 64 + 32 * nw + l31], pacc[mti][rq]);
            }
        }
    }
}

// mean/512 -> max over 16 groups -> dot v -> + fc1b.fc2w + fc2b -> sigmoid
__global__ __launch_bounds__(256) void head(
        const float* __restrict__ gsum, const float* __restrict__ v,
        const float* __restrict__ fc1b, const float* __restrict__ fc2w,
        const float* __restrict__ fc2b, float* __restrict__ out)
{
    __shared__ float sred[256];
    const int tid = threadIdx.x;
    float partial = 0.f;
    const float4* g4 = (const float4*)gsum;
    const float4* v4 = (const float4*)v;
    for (int i = tid; i < 400; i += 256) {
        float4 m = g4[i];
        #pragma unroll
        for (int gg = 1; gg < GROUPS; ++gg) {
            float4 t = g4[gg * 400 + i];
            m.x = fmaxf(m.x, t.x); m.y = fmaxf(m.y, t.y);
            m.z = fmaxf(m.z, t.z); m.w = fmaxf(m.w, t.w);
        }
        float4 vv = v4[i];
        partial += m.x * vv.x + m.y * vv.y + m.z * vv.z + m.w * vv.w;
    }
    partial *= (1.f / 512.f);
    partial += fc1b[tid] * fc2w[tid] + fc1b[tid + 256] * fc2w[tid + 256];
    sred[tid] = partial;
    __syncthreads();
    for (int s = 128; s > 0; s >>= 1) {
        if (tid < s) sred[tid] += sred[tid + s];
        __syncthreads();
    }
    if (tid == 0) out[0] = 1.f / (1.f + expf(-(sred[0] + fc2b[0])));
}

extern "C" void kernel_launch(void* const* d_in, const int* in_sizes, int n_in,
                              void* d_out, int out_size, void* d_ws, size_t ws_size,
                              hipStream_t stream)
{
    const float* x    = (const float*)d_in[0];
    const float* w1   = (const float*)d_in[1];
    const float* b1   = (const float*)d_in[2];
    const float* w2   = (const float*)d_in[3];
    const float* b2   = (const float*)d_in[4];
    const float* fc1w = (const float*)d_in[5];
    const float* fc1b = (const float*)d_in[6];
    const float* fc2w = (const float*)d_in[7];
    const float* fc2b = (const float*)d_in[8];

    float* gsum = (float*)d_ws;
    unsigned char* w2f8 = (unsigned char*)d_ws + WS_W2F8;
    unsigned short* w1f = (unsigned short*)((char*)d_ws + WS_W1F);
    float* v = (float*)((char*)d_ws + WS_V);

    prep<<<582, 256, 0, stream>>>(w1, w2, fc1w, fc2w, gsum, w1f, w2f8, v);
    fused<<<N_IMG / IPB, 256, 0, stream>>>(x, w1f, b1, w2f8, b2, gsum);
    head<<<1, 256, 0, stream>>>(gsum, v, fc1b, fc2w, fc2b, (float*)d_out);
}